// Round 6
// baseline (126.621 us; speedup 1.0000x reference)
//
#include <hip/hip_runtime.h>

#define D 128
#define NT64 8256           // 128*129/2 upper-triangular 64x64 tiles

typedef __attribute__((ext_vector_type(8))) short short8;   // 8 x bf16 (4 VGPRs)
typedef __attribute__((ext_vector_type(4))) float float4v;  // 4 x f32 acc

static __device__ __forceinline__ unsigned short f2bf(float f) {
    unsigned int u = __float_as_uint(f);
    unsigned int r = (u + 0x7fffu + ((u >> 16) & 1u)) >> 16;  // RNE
    return (unsigned short)r;
}

// ws float-index layout (plain stores only, nothing needs zeroing):
//   [4]              c4                   (k_c4)
//   [8..263]         ssq[256]             (k_stats block partials)
//   [512..33279]     colpart[256*128]     (k_stats block partial column sums)
//   [33280..41471]   rowsq[8192]          (k_stats)
//   [41472..49727]   partial[8256]        (mmd, one per 64x64 tile)
//   [65536..]        xbf: bf16 X in FRAGMENT-MAJOR tiled layout (2 MB)
//                    chunk c (8 bf16) of row r -> uint4 index (r>>4)*256 + c*16 + (r&15)

// ---- K1: rowsq + tiled bf16 convert + block-partial column sums ----
// 256 blocks x 256 thr; block = 32 rows of one half (blocks 0-127 src, 128-255 tgt).
__global__ __launch_bounds__(256) void k_stats(const float* __restrict__ src,
                                               const float* __restrict__ tgt,
                                               float* __restrict__ wsf,
                                               uint4* __restrict__ XT) {
    float* ssq = wsf + 8;
    float* colpart = wsf + 512;
    float* rowsq = wsf + 33280;
    __shared__ float colacc[128];
    __shared__ float ssh[4];

    const int tid = threadIdx.x, lane = tid & 63, wv = tid >> 6;
    if (tid < 128) colacc[tid] = 0.f;
    __syncthreads();

    const int rg = lane >> 4;      // row-in-group (0..3)
    const int c = lane & 15;       // 16B chunk = 8 floats
    const int half = blockIdx.x >> 7;
    const float* Xb = half ? tgt : src;
    const int rbase = (blockIdx.x & 127) * 32;

    float colr[8] = {0.f, 0.f, 0.f, 0.f, 0.f, 0.f, 0.f, 0.f};
    float sqacc = 0.f;
    #pragma unroll
    for (int it = 0; it < 2; ++it) {
        int r = rbase + wv * 8 + it * 4 + rg;   // row within half
        int gr = r + half * 4096;                // global row
        const float4* P = (const float4*)(Xb + (size_t)r * D + c * 8);
        float4 f0 = P[0], f1 = P[1];
        union { unsigned short u[8]; uint4 v; } k;
        k.u[0] = f2bf(f0.x); k.u[1] = f2bf(f0.y); k.u[2] = f2bf(f0.z); k.u[3] = f2bf(f0.w);
        k.u[4] = f2bf(f1.x); k.u[5] = f2bf(f1.y); k.u[6] = f2bf(f1.z); k.u[7] = f2bf(f1.w);
        XT[(gr >> 4) * 256 + c * 16 + (gr & 15)] = k.v;
        float s = (f0.x * f0.x + f0.y * f0.y + f0.z * f0.z + f0.w * f0.w) +
                  (f1.x * f1.x + f1.y * f1.y + f1.z * f1.z + f1.w * f1.w);
        sqacc += s;
        colr[0] += f0.x; colr[1] += f0.y; colr[2] += f0.z; colr[3] += f0.w;
        colr[4] += f1.x; colr[5] += f1.y; colr[6] += f1.z; colr[7] += f1.w;
        #pragma unroll
        for (int off = 8; off; off >>= 1) s += __shfl_down(s, off, 16);
        if (c == 0) rowsq[gr] = s;
    }
    #pragma unroll
    for (int off = 32; off; off >>= 1) sqacc += __shfl_down(sqacc, off);
    if (lane == 0) ssh[wv] = sqacc;
    #pragma unroll
    for (int j = 0; j < 8; ++j) atomicAdd(&colacc[c * 8 + j], colr[j]);  // LDS atomics
    __syncthreads();
    if (tid < 128) colpart[blockIdx.x * 128 + tid] = colacc[tid];
    if (tid == 0) ssq[blockIdx.x] = (ssh[0] + ssh[1]) + (ssh[2] + ssh[3]);
}

// ---- K2: reduce k_stats partials -> bandwidth constant c4 (1 block) ----
__global__ __launch_bounds__(256) void k_c4(float* __restrict__ wsf) {
    const float* ssq = wsf + 8;
    const float* colpart = wsf + 512;
    const int tid = threadIdx.x, lane = tid & 63;

    double s = (double)ssq[tid];
    #pragma unroll
    for (int off = 32; off; off >>= 1) s += __shfl_down(s, off);
    __shared__ double dsh[4];
    __shared__ float csum[128];
    __shared__ float vsh[4];
    if (lane == 0) dsh[tid >> 6] = s;

    int c = tid & 127, h = tid >> 7;
    float cs = 0.f;
    for (int b = h * 128; b < h * 128 + 128; ++b) cs += colpart[b * 128 + c];
    __syncthreads();
    if (h == 0) csum[c] = cs;
    __syncthreads();
    if (h == 1) csum[c] += cs;
    __syncthreads();
    float v = (tid < 128) ? csum[tid] * csum[tid] : 0.f;
    #pragma unroll
    for (int off = 32; off; off >>= 1) v += __shfl_down(v, off);
    if (lane == 0) vsh[tid >> 6] = v;
    __syncthreads();
    if (tid == 0) {
        double ss = (dsh[0] + dsh[1]) + (dsh[2] + dsh[3]);
        double s2 = (double)vsh[0] + vsh[1] + vsh[2] + vsh[3];
        double sumL2 = 2.0 * 8192.0 * ss - 2.0 * s2;
        double bw = sumL2 / (8192.0 * 8192.0 - 8192.0) / 4.0;  // /KERNEL_MUL^(5/2)
        wsf[4] = (float)(-1.4426950408889634 / (bw * 16.0));   // c4
    }
}

// ---- M: one 64x64 tile per wave, fragments loaded DIRECTLY from L2-resident
//      tiled xbf (1 KB contiguous per load). No LDS tiles, no barriers. ----
__global__ __launch_bounds__(256, 4) void mmd_main(const uint4* __restrict__ XT,
                                                   const float* __restrict__ wsf,
                                                   float* __restrict__ partial) {
    const float* rowsq = wsf + 33280;
    const int lane = threadIdx.x & 63, wv = threadIdx.x >> 6;
    const int quad = lane >> 4, mrow = lane & 15;

    // tile id -> (ti <= tj) over 128 row-panels; base(b) = b*(257-b)/2
    int t = blockIdx.x * 4 + wv;
    int ti = (int)((257.0 - sqrt(257.0 * 257.0 - 8.0 * (double)t)) * 0.5);
    auto base = [](int b) { return (b * (257 - b)) >> 1; };
    while (base(ti + 1) <= t) ++ti;
    while (base(ti) > t) --ti;
    int tj = ti + (t - base(ti));

    const uint4* A = XT + (size_t)ti * 1024;   // 4 row-blocks x 256 chunks
    const uint4* B = XT + (size_t)tj * 1024;
    float c4 = wsf[4];

    float4v acc[4][4];
    #pragma unroll
    for (int mt = 0; mt < 4; ++mt)
        #pragma unroll
        for (int nt = 0; nt < 4; ++nt)
            acc[mt][nt] = (float4v){0.f, 0.f, 0.f, 0.f};

    #pragma unroll
    for (int kc = 0; kc < 4; ++kc) {
        short8 af[4], bf[4];
        #pragma unroll
        for (int mt = 0; mt < 4; ++mt)
            af[mt] = *(const short8*)&A[mt * 256 + kc * 64 + lane];
        #pragma unroll
        for (int nt = 0; nt < 4; ++nt)
            bf[nt] = *(const short8*)&B[nt * 256 + kc * 64 + lane];
        #pragma unroll
        for (int mt = 0; mt < 4; ++mt)
            #pragma unroll
            for (int nt = 0; nt < 4; ++nt)
                acc[mt][nt] = __builtin_amdgcn_mfma_f32_16x16x32_bf16(af[mt], bf[nt], acc[mt][nt], 0, 0, 0);
    }

    // epilogue: e = exp2(fma(d, -2*c4, rA*c4 + rB*c4)); sum e^{1,2,4,8,16}
    const float* rsqA = rowsq + ti * 64;
    const float* rsqB = rowsq + tj * 64;
    const float cm2 = -2.f * c4;
    float part = 0.f;
    #pragma unroll
    for (int mt = 0; mt < 4; ++mt) {
        float rAc[4];
        #pragma unroll
        for (int r = 0; r < 4; ++r) rAc[r] = rsqA[mt * 16 + quad * 4 + r] * c4;
        #pragma unroll
        for (int nt = 0; nt < 4; ++nt) {
            float rBc = rsqB[nt * 16 + mrow] * c4;
            float4v d = acc[mt][nt];
            #pragma unroll
            for (int r = 0; r < 4; ++r) {
                float e1 = __builtin_amdgcn_exp2f(__builtin_fmaf(d[r], cm2, rAc[r] + rBc));
                float e2 = e1 * e1, e4 = e2 * e2, e8 = e4 * e4, e16 = e8 * e8;
                part += ((e1 + e2) + (e4 + e8)) + e16;
            }
        }
    }
    #pragma unroll
    for (int off = 32; off; off >>= 1) part += __shfl_down(part, off);
    if (lane == 0) {
        float wgt = ((ti < 64) == (tj < 64)) ? 1.f : -1.f;  // XX/YY vs XY/YX sign
        if (ti != tj) wgt *= 2.f;                           // symmetric off-diagonal
        partial[t] = wgt * part;
    }
}

// ---- F: reduce per-tile partials in fp64, scale, emit ----
__global__ __launch_bounds__(256) void f_final(const float* __restrict__ wsf,
                                               float* __restrict__ out) {
    const float* partial = wsf + 41472;
    int tid = threadIdx.x, lane = tid & 63;
    double s = 0.0;
    for (int i = tid; i < NT64; i += 256) s += (double)partial[i];
    #pragma unroll
    for (int off = 32; off; off >>= 1) s += __shfl_down(s, off);
    __shared__ double r4[4];
    if (lane == 0) r4[tid >> 6] = s;
    __syncthreads();
    if (tid == 0)
        out[0] = (float)(((r4[0] + r4[1]) + (r4[2] + r4[3])) * (1.0 / (4096.0 * 4096.0)));
}

extern "C" void kernel_launch(void* const* d_in, const int* in_sizes, int n_in,
                              void* d_out, int out_size, void* d_ws, size_t ws_size,
                              hipStream_t stream) {
    const float* src = (const float*)d_in[0];
    const float* tgt = (const float*)d_in[1];
    float* wsf = (float*)d_ws;
    uint4* XT = (uint4*)(wsf + 65536);          // byte 256K, 2 MB tiled bf16
    float* partial = wsf + 41472;

    hipLaunchKernelGGL(k_stats, dim3(256), dim3(256), 0, stream, src, tgt, wsf, XT);
    hipLaunchKernelGGL(k_c4, dim3(1), dim3(256), 0, stream, wsf);
    hipLaunchKernelGGL(mmd_main, dim3(NT64 / 4), dim3(256), 0, stream, XT, wsf, partial);
    hipLaunchKernelGGL(f_final, dim3(1), dim3(256), 0, stream, wsf, (float*)d_out);
}

// Round 7
// 95.500 us; speedup vs baseline: 1.3259x; 1.3259x over previous
//
#include <hip/hip_runtime.h>

#define D 128
#define NT64 8256           // 128*129/2 upper-triangular 64x64 tiles

typedef __attribute__((ext_vector_type(8))) short short8;   // 8 x bf16 (4 VGPRs)
typedef __attribute__((ext_vector_type(4))) float float4v;  // 4 x f32 acc

static __device__ __forceinline__ unsigned short f2bf(float f) {
    unsigned int u = __float_as_uint(f);
    unsigned int r = (u + 0x7fffu + ((u >> 16) & 1u)) >> 16;  // RNE
    return (unsigned short)r;
}

// ws float-index layout (plain stores only, nothing needs zeroing):
//   [4]              c4                   (p3_consts)
//   [512..16895]     colpart[128*128]     (p2_colpart block partial column sums)
//   [33280..41471]   rowsq[8192]          (k_conv)
//   [41472..49727]   partial[8256]        (mmd, one per 64x64 tile)
//   [65536..]        XT: bf16 X, FRAGMENT-MAJOR tiled (2 MB)
//                    8-bf16 chunk c of row r -> uint4 idx (r>>4)*256 + c*16 + (r&15)

// ---- P1: rowsq + tiled bf16 convert. One wave per row (r3's shape). ----
__global__ __launch_bounds__(256) void k_conv(const float* __restrict__ src,
                                              const float* __restrict__ tgt,
                                              float* __restrict__ wsf,
                                              unsigned int* __restrict__ XTu) {
    float* rowsq = wsf + 33280;
    const int wv = threadIdx.x >> 6, lane = threadIdx.x & 63;
    const int gr = blockIdx.x * 4 + wv;
    const float* Xr = (gr < 4096) ? src + (size_t)gr * D : tgt + (size_t)(gr - 4096) * D;
    float2 f = ((const float2*)Xr)[lane];
    // tiled store: uint index (r>>4)*1024 + c*64 + (r&15)*4 + (lane&3), c = lane>>2
    XTu[(gr >> 4) * 1024 + (lane >> 2) * 64 + (gr & 15) * 4 + (lane & 3)] =
        (unsigned)f2bf(f.x) | ((unsigned)f2bf(f.y) << 16);
    float s = f.x * f.x + f.y * f.y;
    #pragma unroll
    for (int off = 32; off; off >>= 1) s += __shfl_down(s, off);
    if (lane == 0) rowsq[gr] = s;
}

// ---- P2: block-partial column sums (r3's shape: 128 blocks) ----
__global__ __launch_bounds__(256) void p2_colpart(const float* __restrict__ src,
                                                  const float* __restrict__ tgt,
                                                  float* __restrict__ wsf) {
    float* colpart = wsf + 512;
    int b = blockIdx.x;
    int col = threadIdx.x & 127, half = threadIdx.x >> 7;
    const float* X = (b < 64) ? src + (size_t)(b * 64) * D : tgt + (size_t)((b - 64) * 64) * D;
    float p0 = 0.f, p1 = 0.f, p2 = 0.f, p3 = 0.f;   // independent chains
    #pragma unroll 4
    for (int i = 0; i < 32; i += 4) {
        p0 += X[(size_t)(2 * (i + 0) + half) * D + col];
        p1 += X[(size_t)(2 * (i + 1) + half) * D + col];
        p2 += X[(size_t)(2 * (i + 2) + half) * D + col];
        p3 += X[(size_t)(2 * (i + 3) + half) * D + col];
    }
    __shared__ float cp[2][128];
    cp[half][col] = (p0 + p1) + (p2 + p3);
    __syncthreads();
    if (threadIdx.x < 128) colpart[b * 128 + threadIdx.x] = cp[0][threadIdx.x] + cp[1][threadIdx.x];
}

// ---- P3: reduce -> bandwidth constant c4 (1 block, latency-tolerant) ----
__global__ __launch_bounds__(256) void p3_consts(float* __restrict__ wsf) {
    const float* colpart = wsf + 512;
    const float* rowsq = wsf + 33280;
    const int tid = threadIdx.x, lane = tid & 63;

    float s0 = 0.f, s1 = 0.f, s2 = 0.f, s3 = 0.f;   // sum of rowsq (= sum of squares)
    #pragma unroll
    for (int i = 0; i < 32; i += 4) {
        s0 += rowsq[tid + 256 * (i + 0)];
        s1 += rowsq[tid + 256 * (i + 1)];
        s2 += rowsq[tid + 256 * (i + 2)];
        s3 += rowsq[tid + 256 * (i + 3)];
    }
    float s = (s0 + s1) + (s2 + s3);
    #pragma unroll
    for (int off = 32; off; off >>= 1) s += __shfl_down(s, off);
    __shared__ float red[8];
    __shared__ float csum[128];
    if (lane == 0) red[tid >> 6] = s;

    int c = tid & 127, h = tid >> 7;                 // column c, half h of the 128 blocks
    float q0 = 0.f, q1 = 0.f, q2 = 0.f, q3 = 0.f;
    #pragma unroll 4
    for (int b = 0; b < 64; b += 4) {
        q0 += colpart[(h * 64 + b + 0) * 128 + c];
        q1 += colpart[(h * 64 + b + 1) * 128 + c];
        q2 += colpart[(h * 64 + b + 2) * 128 + c];
        q3 += colpart[(h * 64 + b + 3) * 128 + c];
    }
    float cs = (q0 + q1) + (q2 + q3);
    __syncthreads();
    if (h == 0) csum[c] = cs;
    __syncthreads();
    if (h == 1) csum[c] += cs;
    __syncthreads();
    float v = (tid < 128) ? csum[tid] * csum[tid] : 0.f;
    #pragma unroll
    for (int off = 32; off; off >>= 1) v += __shfl_down(v, off);
    if (lane == 0) red[4 + (tid >> 6)] = v;
    __syncthreads();
    if (tid == 0) {
        double ss = (double)red[0] + red[1] + red[2] + red[3];
        double s2 = (double)red[4] + red[5] + red[6] + red[7];
        double sumL2 = 2.0 * 8192.0 * ss - 2.0 * s2;
        double bw = sumL2 / (8192.0 * 8192.0 - 8192.0) / 4.0;  // /KERNEL_MUL^(5/2)
        wsf[4] = (float)(-1.4426950408889634 / (bw * 16.0));   // c4
    }
}

// ---- M: one 64x64 tile per wave, fragments straight from L2-resident tiled XT
//      (1 KB contiguous per b128 load). No LDS tiles, no barriers. ----
__global__ __launch_bounds__(256, 4) void mmd_main(const uint4* __restrict__ XT,
                                                   const float* __restrict__ wsf,
                                                   float* __restrict__ partial) {
    const float* rowsq = wsf + 33280;
    const int lane = threadIdx.x & 63, wv = threadIdx.x >> 6;
    const int quad = lane >> 4, mrow = lane & 15;

    // tile id -> (ti <= tj) over 128 row-panels; base(b) = b*(257-b)/2
    int t = blockIdx.x * 4 + wv;
    int ti = (int)((257.0 - sqrt(257.0 * 257.0 - 8.0 * (double)t)) * 0.5);
    auto base = [](int b) { return (b * (257 - b)) >> 1; };
    while (base(ti + 1) <= t) ++ti;
    while (base(ti) > t) --ti;
    int tj = ti + (t - base(ti));

    const uint4* A = XT + (size_t)ti * 1024;   // 4 row-blocks x 256 chunks
    const uint4* B = XT + (size_t)tj * 1024;
    float c4 = wsf[4];

    float4v acc[4][4];
    #pragma unroll
    for (int mt = 0; mt < 4; ++mt)
        #pragma unroll
        for (int nt = 0; nt < 4; ++nt)
            acc[mt][nt] = (float4v){0.f, 0.f, 0.f, 0.f};

    #pragma unroll
    for (int kc = 0; kc < 4; ++kc) {
        short8 af[4], bf[4];
        #pragma unroll
        for (int mt = 0; mt < 4; ++mt)
            af[mt] = *(const short8*)&A[mt * 256 + kc * 64 + lane];
        #pragma unroll
        for (int nt = 0; nt < 4; ++nt)
            bf[nt] = *(const short8*)&B[nt * 256 + kc * 64 + lane];
        #pragma unroll
        for (int mt = 0; mt < 4; ++mt)
            #pragma unroll
            for (int nt = 0; nt < 4; ++nt)
                acc[mt][nt] = __builtin_amdgcn_mfma_f32_16x16x32_bf16(af[mt], bf[nt], acc[mt][nt], 0, 0, 0);
    }

    // epilogue: e = exp2(fma(d, -2*c4, rA*c4 + rB*c4)); sum e^{1,2,4,8,16}
    const float* rsqA = rowsq + ti * 64;
    const float* rsqB = rowsq + tj * 64;
    const float cm2 = -2.f * c4;
    float part = 0.f;
    #pragma unroll
    for (int mt = 0; mt < 4; ++mt) {
        float rAc[4];
        #pragma unroll
        for (int r = 0; r < 4; ++r) rAc[r] = rsqA[mt * 16 + quad * 4 + r] * c4;
        #pragma unroll
        for (int nt = 0; nt < 4; ++nt) {
            float rBc = rsqB[nt * 16 + mrow] * c4;
            float4v d = acc[mt][nt];
            #pragma unroll
            for (int r = 0; r < 4; ++r) {
                float e1 = __builtin_amdgcn_exp2f(__builtin_fmaf(d[r], cm2, rAc[r] + rBc));
                float e2 = e1 * e1, e4 = e2 * e2, e8 = e4 * e4, e16 = e8 * e8;
                part += ((e1 + e2) + (e4 + e8)) + e16;
            }
        }
    }
    #pragma unroll
    for (int off = 32; off; off >>= 1) part += __shfl_down(part, off);
    if (lane == 0) {
        float wgt = ((ti < 64) == (tj < 64)) ? 1.f : -1.f;  // XX/YY vs XY/YX sign
        if (ti != tj) wgt *= 2.f;                           // symmetric off-diagonal
        partial[t] = wgt * part;
    }
}

// ---- F: reduce per-tile partials in fp64 (independent chains), scale, emit ----
__global__ __launch_bounds__(256) void f_final(const float* __restrict__ wsf,
                                               float* __restrict__ out) {
    const float* partial = wsf + 41472;
    int tid = threadIdx.x, lane = tid & 63;
    double a0 = 0.0, a1 = 0.0, a2 = 0.0, a3 = 0.0;
    #pragma unroll 4
    for (int i = tid; i < NT64; i += 1024) {
        a0 += (double)partial[i];
        if (i + 256 < NT64) a1 += (double)partial[i + 256];
        if (i + 512 < NT64) a2 += (double)partial[i + 512];
        if (i + 768 < NT64) a3 += (double)partial[i + 768];
    }
    double s = (a0 + a1) + (a2 + a3);
    #pragma unroll
    for (int off = 32; off; off >>= 1) s += __shfl_down(s, off);
    __shared__ double r4[4];
    if (lane == 0) r4[tid >> 6] = s;
    __syncthreads();
    if (tid == 0)
        out[0] = (float)(((r4[0] + r4[1]) + (r4[2] + r4[3])) * (1.0 / (4096.0 * 4096.0)));
}

extern "C" void kernel_launch(void* const* d_in, const int* in_sizes, int n_in,
                              void* d_out, int out_size, void* d_ws, size_t ws_size,
                              hipStream_t stream) {
    const float* src = (const float*)d_in[0];
    const float* tgt = (const float*)d_in[1];
    float* wsf = (float*)d_ws;
    unsigned int* XTu = (unsigned int*)(wsf + 65536);   // byte 256K, 2 MB tiled bf16
    float* partial = wsf + 41472;

    hipLaunchKernelGGL(k_conv, dim3(2048), dim3(256), 0, stream, src, tgt, wsf, XTu);
    hipLaunchKernelGGL(p2_colpart, dim3(128), dim3(256), 0, stream, src, tgt, wsf);
    hipLaunchKernelGGL(p3_consts, dim3(1), dim3(256), 0, stream, wsf);
    hipLaunchKernelGGL(mmd_main, dim3(NT64 / 4), dim3(256), 0, stream,
                       (const uint4*)XTu, wsf, partial);
    hipLaunchKernelGGL(f_final, dim3(1), dim3(256), 0, stream, wsf, (float*)d_out);
}

// Round 8
// 94.308 us; speedup vs baseline: 1.3426x; 1.0126x over previous
//
#include <hip/hip_runtime.h>

#define D 128
#define NT64 8256           // 128*129/2 upper-triangular 64x64 tiles

typedef __attribute__((ext_vector_type(8))) short short8;   // 8 x bf16 (4 VGPRs)
typedef __attribute__((ext_vector_type(4))) float float4v;  // 4 x f32 acc

static __device__ __forceinline__ unsigned short f2bf(float f) {
    unsigned int u = __float_as_uint(f);
    unsigned int r = (u + 0x7fffu + ((u >> 16) & 1u)) >> 16;  // RNE
    return (unsigned short)r;
}

// ws float-index layout (plain stores only, nothing needs zeroing):
//   [4]              c4                   (p3_consts)
//   [512..16895]     colpart[128*128]     (k_prep colpart section)
//   [33280..41471]   rowsq[8192]          (k_prep convert section)
//   [41472..49727]   partial[8256]        (mmd, one per 64x64 tile)
//   [65536..]        XT: bf16 X, FRAGMENT-MAJOR tiled (2 MB)
//                    8-bf16 chunk c of row r -> uint4 idx (r>>4)*256 + c*16 + (r&15)

// ---- P1+P2 fused in one dispatch (independent grid sections, both read only X):
//      blocks [0,2048): rowsq + tiled bf16 convert, one wave per row
//      blocks [2048,2176): block-partial column sums (b = blockIdx - 2048)
__global__ __launch_bounds__(256) void k_prep(const float* __restrict__ src,
                                              const float* __restrict__ tgt,
                                              float* __restrict__ wsf,
                                              unsigned int* __restrict__ XTu) {
    if (blockIdx.x < 2048) {
        float* rowsq = wsf + 33280;
        const int wv = threadIdx.x >> 6, lane = threadIdx.x & 63;
        const int gr = blockIdx.x * 4 + wv;
        const float* Xr = (gr < 4096) ? src + (size_t)gr * D : tgt + (size_t)(gr - 4096) * D;
        float2 f = ((const float2*)Xr)[lane];
        // tiled store: uint index (r>>4)*1024 + c*64 + (r&15)*4 + (lane&3), c = lane>>2
        XTu[(gr >> 4) * 1024 + (lane >> 2) * 64 + (gr & 15) * 4 + (lane & 3)] =
            (unsigned)f2bf(f.x) | ((unsigned)f2bf(f.y) << 16);
        float s = f.x * f.x + f.y * f.y;
        #pragma unroll
        for (int off = 32; off; off >>= 1) s += __shfl_down(s, off);
        if (lane == 0) rowsq[gr] = s;
    } else {
        float* colpart = wsf + 512;
        int b = blockIdx.x - 2048;
        int col = threadIdx.x & 127, half = threadIdx.x >> 7;
        const float* X = (b < 64) ? src + (size_t)(b * 64) * D
                                  : tgt + (size_t)((b - 64) * 64) * D;
        float p0 = 0.f, p1 = 0.f, p2 = 0.f, p3 = 0.f;   // independent chains
        #pragma unroll 4
        for (int i = 0; i < 32; i += 4) {
            p0 += X[(size_t)(2 * (i + 0) + half) * D + col];
            p1 += X[(size_t)(2 * (i + 1) + half) * D + col];
            p2 += X[(size_t)(2 * (i + 2) + half) * D + col];
            p3 += X[(size_t)(2 * (i + 3) + half) * D + col];
        }
        __shared__ float cp[2][128];
        cp[half][col] = (p0 + p1) + (p2 + p3);
        __syncthreads();
        if (threadIdx.x < 128)
            colpart[b * 128 + threadIdx.x] = cp[0][threadIdx.x] + cp[1][threadIdx.x];
    }
}

// ---- P3: reduce -> bandwidth constant c4 (1 block, latency-tolerant) ----
__global__ __launch_bounds__(256) void p3_consts(float* __restrict__ wsf) {
    const float* colpart = wsf + 512;
    const float* rowsq = wsf + 33280;
    const int tid = threadIdx.x, lane = tid & 63;

    float s0 = 0.f, s1 = 0.f, s2 = 0.f, s3 = 0.f;   // sum of rowsq (= sum of squares)
    #pragma unroll
    for (int i = 0; i < 32; i += 4) {
        s0 += rowsq[tid + 256 * (i + 0)];
        s1 += rowsq[tid + 256 * (i + 1)];
        s2 += rowsq[tid + 256 * (i + 2)];
        s3 += rowsq[tid + 256 * (i + 3)];
    }
    float s = (s0 + s1) + (s2 + s3);
    #pragma unroll
    for (int off = 32; off; off >>= 1) s += __shfl_down(s, off);
    __shared__ float red[8];
    __shared__ float csum[128];
    if (lane == 0) red[tid >> 6] = s;

    int c = tid & 127, h = tid >> 7;                 // column c, half h of the 128 blocks
    float q0 = 0.f, q1 = 0.f, q2 = 0.f, q3 = 0.f;
    #pragma unroll 4
    for (int b = 0; b < 64; b += 4) {
        q0 += colpart[(h * 64 + b + 0) * 128 + c];
        q1 += colpart[(h * 64 + b + 1) * 128 + c];
        q2 += colpart[(h * 64 + b + 2) * 128 + c];
        q3 += colpart[(h * 64 + b + 3) * 128 + c];
    }
    float cs = (q0 + q1) + (q2 + q3);
    __syncthreads();
    if (h == 0) csum[c] = cs;
    __syncthreads();
    if (h == 1) csum[c] += cs;
    __syncthreads();
    float v = (tid < 128) ? csum[tid] * csum[tid] : 0.f;
    #pragma unroll
    for (int off = 32; off; off >>= 1) v += __shfl_down(v, off);
    if (lane == 0) red[4 + (tid >> 6)] = v;
    __syncthreads();
    if (tid == 0) {
        double ss = (double)red[0] + red[1] + red[2] + red[3];
        double s2 = (double)red[4] + red[5] + red[6] + red[7];
        double sumL2 = 2.0 * 8192.0 * ss - 2.0 * s2;
        double bw = sumL2 / (8192.0 * 8192.0 - 8192.0) / 4.0;  // /KERNEL_MUL^(5/2)
        wsf[4] = (float)(-1.4426950408889634 / (bw * 16.0));   // c4
    }
}

// ---- M: one 64x64 tile per wave, fragments straight from L2-resident tiled XT
//      (1 KB contiguous per b128 load). No LDS tiles, no barriers. ----
__global__ __launch_bounds__(256, 4) void mmd_main(const uint4* __restrict__ XT,
                                                   const float* __restrict__ wsf,
                                                   float* __restrict__ partial) {
    const float* rowsq = wsf + 33280;
    const int lane = threadIdx.x & 63, wv = threadIdx.x >> 6;
    const int quad = lane >> 4, mrow = lane & 15;

    // tile id -> (ti <= tj) over 128 row-panels; base(b) = b*(257-b)/2
    int t = blockIdx.x * 4 + wv;
    int ti = (int)((257.0 - sqrt(257.0 * 257.0 - 8.0 * (double)t)) * 0.5);
    auto base = [](int b) { return (b * (257 - b)) >> 1; };
    while (base(ti + 1) <= t) ++ti;
    while (base(ti) > t) --ti;
    int tj = ti + (t - base(ti));

    const uint4* A = XT + (size_t)ti * 1024;   // 4 row-blocks x 256 chunks
    const uint4* B = XT + (size_t)tj * 1024;
    float c4 = wsf[4];

    float4v acc[4][4];
    #pragma unroll
    for (int mt = 0; mt < 4; ++mt)
        #pragma unroll
        for (int nt = 0; nt < 4; ++nt)
            acc[mt][nt] = (float4v){0.f, 0.f, 0.f, 0.f};

    #pragma unroll
    for (int kc = 0; kc < 4; ++kc) {
        short8 af[4], bf[4];
        #pragma unroll
        for (int mt = 0; mt < 4; ++mt)
            af[mt] = *(const short8*)&A[mt * 256 + kc * 64 + lane];
        #pragma unroll
        for (int nt = 0; nt < 4; ++nt)
            bf[nt] = *(const short8*)&B[nt * 256 + kc * 64 + lane];
        #pragma unroll
        for (int mt = 0; mt < 4; ++mt)
            #pragma unroll
            for (int nt = 0; nt < 4; ++nt)
                acc[mt][nt] = __builtin_amdgcn_mfma_f32_16x16x32_bf16(af[mt], bf[nt], acc[mt][nt], 0, 0, 0);
    }

    // epilogue: e = exp2(fma(d, -2*c4, rA*c4 + rB*c4)); sum e^{1,2,4,8,16}
    const float* rsqA = rowsq + ti * 64;
    const float* rsqB = rowsq + tj * 64;
    const float cm2 = -2.f * c4;
    float part = 0.f;
    #pragma unroll
    for (int mt = 0; mt < 4; ++mt) {
        float rAc[4];
        #pragma unroll
        for (int r = 0; r < 4; ++r) rAc[r] = rsqA[mt * 16 + quad * 4 + r] * c4;
        #pragma unroll
        for (int nt = 0; nt < 4; ++nt) {
            float rBc = rsqB[nt * 16 + mrow] * c4;
            float4v d = acc[mt][nt];
            #pragma unroll
            for (int r = 0; r < 4; ++r) {
                float e1 = __builtin_amdgcn_exp2f(__builtin_fmaf(d[r], cm2, rAc[r] + rBc));
                float e2 = e1 * e1, e4 = e2 * e2, e8 = e4 * e4, e16 = e8 * e8;
                part += ((e1 + e2) + (e4 + e8)) + e16;
            }
        }
    }
    #pragma unroll
    for (int off = 32; off; off >>= 1) part += __shfl_down(part, off);
    if (lane == 0) {
        float wgt = ((ti < 64) == (tj < 64)) ? 1.f : -1.f;  // XX/YY vs XY/YX sign
        if (ti != tj) wgt *= 2.f;                           // symmetric off-diagonal
        partial[t] = wgt * part;
    }
}

// ---- F: reduce per-tile partials in fp64 (independent chains), scale, emit ----
__global__ __launch_bounds__(256) void f_final(const float* __restrict__ wsf,
                                               float* __restrict__ out) {
    const float* partial = wsf + 41472;
    int tid = threadIdx.x, lane = tid & 63;
    double a0 = 0.0, a1 = 0.0, a2 = 0.0, a3 = 0.0;
    #pragma unroll 4
    for (int i = tid; i < NT64; i += 1024) {
        a0 += (double)partial[i];
        if (i + 256 < NT64) a1 += (double)partial[i + 256];
        if (i + 512 < NT64) a2 += (double)partial[i + 512];
        if (i + 768 < NT64) a3 += (double)partial[i + 768];
    }
    double s = (a0 + a1) + (a2 + a3);
    #pragma unroll
    for (int off = 32; off; off >>= 1) s += __shfl_down(s, off);
    __shared__ double r4[4];
    if (lane == 0) r4[tid >> 6] = s;
    __syncthreads();
    if (tid == 0)
        out[0] = (float)(((r4[0] + r4[1]) + (r4[2] + r4[3])) * (1.0 / (4096.0 * 4096.0)));
}

extern "C" void kernel_launch(void* const* d_in, const int* in_sizes, int n_in,
                              void* d_out, int out_size, void* d_ws, size_t ws_size,
                              hipStream_t stream) {
    const float* src = (const float*)d_in[0];
    const float* tgt = (const float*)d_in[1];
    float* wsf = (float*)d_ws;
    unsigned int* XTu = (unsigned int*)(wsf + 65536);   // byte 256K, 2 MB tiled bf16
    float* partial = wsf + 41472;

    hipLaunchKernelGGL(k_prep, dim3(2176), dim3(256), 0, stream, src, tgt, wsf, XTu);
    hipLaunchKernelGGL(p3_consts, dim3(1), dim3(256), 0, stream, wsf);
    hipLaunchKernelGGL(mmd_main, dim3(NT64 / 4), dim3(256), 0, stream,
                       (const uint4*)XTu, wsf, partial);
    hipLaunchKernelGGL(f_final, dim3(1), dim3(256), 0, stream, wsf, (float*)d_out);
}